// Round 1
// baseline (569.139 us; speedup 1.0000x reference)
//
#include <hip/hip_runtime.h>
#include <math.h>

#define NN 65536
#define MM 16384
#define EE 524288
#define CF 64
#define HD 128
#define OD 256

// order-isomorphic float->uint encoding so segment-max can use atomicMax(uint)
__device__ __forceinline__ unsigned enc_f(float f) {
    unsigned u = __float_as_uint(f);
    return (u & 0x80000000u) ? ~u : (u | 0x80000000u);
}
__device__ __forceinline__ float dec_f(unsigned e) {
    unsigned u = (e & 0x80000000u) ? (e ^ 0x80000000u) : ~e;
    return __uint_as_float(u);
}
#define ENC_NEG_INF 0x007FFFFFu  // enc(-inf)

__global__ void k_init(unsigned* __restrict__ agg) {
    int i = blockIdx.x * 256 + threadIdx.x;
    if (i < MM * HD) agg[i] = ENC_NEG_INF;
}

__global__ void k_prep(const float* __restrict__ pos, const int* __restrict__ batch,
                       const int* __restrict__ idx, float* __restrict__ out) {
    int m = blockIdx.x * 256 + threadIdx.x;
    if (m >= MM) return;
    int s = idx[m];
    out[MM * OD + m * 3 + 0] = pos[s * 3 + 0];
    out[MM * OD + m * 3 + 1] = pos[s * 3 + 1];
    out[MM * OD + m * 3 + 2] = pos[s * 3 + 2];
    out[MM * OD + MM * 3 + m] = (float)batch[s];
}

// 64 edges per block. edge_in = [ x[col] (64) | pd (3) | sin/cos interleaved (60) ] = 127, pad to 128.
__launch_bounds__(256, 2)
__global__ void k_edge(const float* __restrict__ x, const float* __restrict__ pos,
                       const int* __restrict__ idx, const int* __restrict__ row,
                       const int* __restrict__ col,
                       const float* __restrict__ lw1, const float* __restrict__ lb1,
                       const float* __restrict__ lw2, const float* __restrict__ lb2,
                       unsigned* __restrict__ agg) {
    __shared__ float ein[64][HD];   // edge_in, later reused for edge_feat
    __shared__ float hbuf[64][HD];  // hidden
    __shared__ int srow[64];
    const int t = threadIdx.x;
    const int e0 = blockIdx.x * 64;

    // ---- stage x[col] into ein[:,0:64] (4 threads per edge, float4) ----
    {
        int e = t >> 2, part = t & 3;
        int c = col[e0 + e];
        const float4* xr = (const float4*)(x + (size_t)c * CF);
        float4* er = (float4*)(&ein[e][0]);
        #pragma unroll
        for (int q = 0; q < 4; ++q) er[part * 4 + q] = xr[part * 4 + q];
    }
    // ---- positional encoding into ein[:,64:127] ----
    if (t < 64) {
        int e = t;
        int r = row[e0 + e];
        srow[e] = r;
        int c = col[e0 + e];
        int s = idx[r];
        float pd[3];
        #pragma unroll
        for (int d = 0; d < 3; ++d) pd[d] = pos[c * 3 + d] - pos[s * 3 + d];
        ein[e][64] = pd[0]; ein[e][65] = pd[1]; ein[e][66] = pd[2];
        #pragma unroll
        for (int d = 0; d < 3; ++d) {
            float f = pd[d] * 3.14159265358979323846f;  // *2 each step == coords*(pi*2^l) exactly
            #pragma unroll
            for (int l = 0; l < 10; ++l) {
                float sv, cv;
                sincosf(f, &sv, &cv);
                ein[e][67 + d * 20 + l * 2 + 0] = sv;
                ein[e][67 + d * 20 + l * 2 + 1] = cv;
                f *= 2.0f;
            }
        }
        ein[e][127] = 0.0f;  // pad
    }
    __syncthreads();

    const int j4 = (t & 31) * 4;       // 4 output cols
    const int ebase = (t >> 5) * 8;    // 8 edges

    // ---- GEMM1: h = relu(ein @ lw1 + lb1), K=127 ----
    {
        float acc[8][4];
        const float4 bias = *(const float4*)&lb1[j4];
        #pragma unroll
        for (int r = 0; r < 8; ++r) { acc[r][0] = bias.x; acc[r][1] = bias.y; acc[r][2] = bias.z; acc[r][3] = bias.w; }
        for (int k = 0; k < 124; k += 4) {
            float4 w0 = *(const float4*)&lw1[(k + 0) * HD + j4];
            float4 w1 = *(const float4*)&lw1[(k + 1) * HD + j4];
            float4 w2 = *(const float4*)&lw1[(k + 2) * HD + j4];
            float4 w3 = *(const float4*)&lw1[(k + 3) * HD + j4];
            #pragma unroll
            for (int r = 0; r < 8; ++r) {
                float4 a = *(const float4*)&ein[ebase + r][k];
                acc[r][0] += a.x * w0.x + a.y * w1.x + a.z * w2.x + a.w * w3.x;
                acc[r][1] += a.x * w0.y + a.y * w1.y + a.z * w2.y + a.w * w3.y;
                acc[r][2] += a.x * w0.z + a.y * w1.z + a.z * w2.z + a.w * w3.z;
                acc[r][3] += a.x * w0.w + a.y * w1.w + a.z * w2.w + a.w * w3.w;
            }
        }
        #pragma unroll
        for (int k = 124; k < 127; ++k) {
            float4 w = *(const float4*)&lw1[k * HD + j4];
            #pragma unroll
            for (int r = 0; r < 8; ++r) {
                float a = ein[ebase + r][k];
                acc[r][0] += a * w.x; acc[r][1] += a * w.y; acc[r][2] += a * w.z; acc[r][3] += a * w.w;
            }
        }
        #pragma unroll
        for (int r = 0; r < 8; ++r) {
            float4 hv;
            hv.x = fmaxf(acc[r][0], 0.f); hv.y = fmaxf(acc[r][1], 0.f);
            hv.z = fmaxf(acc[r][2], 0.f); hv.w = fmaxf(acc[r][3], 0.f);
            *(float4*)&hbuf[ebase + r][j4] = hv;
        }
    }
    __syncthreads();

    // ---- GEMM2: ef = h @ lw2 + lb2, K=128; write into ein ----
    {
        float acc[8][4];
        const float4 bias = *(const float4*)&lb2[j4];
        #pragma unroll
        for (int r = 0; r < 8; ++r) { acc[r][0] = bias.x; acc[r][1] = bias.y; acc[r][2] = bias.z; acc[r][3] = bias.w; }
        for (int k = 0; k < 128; k += 4) {
            float4 w0 = *(const float4*)&lw2[(k + 0) * HD + j4];
            float4 w1 = *(const float4*)&lw2[(k + 1) * HD + j4];
            float4 w2 = *(const float4*)&lw2[(k + 2) * HD + j4];
            float4 w3 = *(const float4*)&lw2[(k + 3) * HD + j4];
            #pragma unroll
            for (int r = 0; r < 8; ++r) {
                float4 a = *(const float4*)&hbuf[ebase + r][k];
                acc[r][0] += a.x * w0.x + a.y * w1.x + a.z * w2.x + a.w * w3.x;
                acc[r][1] += a.x * w0.y + a.y * w1.y + a.z * w2.y + a.w * w3.y;
                acc[r][2] += a.x * w0.z + a.y * w1.z + a.z * w2.z + a.w * w3.z;
                acc[r][3] += a.x * w0.w + a.y * w1.w + a.z * w2.w + a.w * w3.w;
            }
        }
        #pragma unroll
        for (int r = 0; r < 8; ++r) {
            float4 v; v.x = acc[r][0]; v.y = acc[r][1]; v.z = acc[r][2]; v.w = acc[r][3];
            *(float4*)&ein[ebase + r][j4] = v;
        }
    }
    __syncthreads();

    // ---- segment max (row sorted): one atomic per (row, feature) run ----
    {
        int j = t & 127;
        int eb = (t >> 7) * 32;
        int cur = srow[eb];
        float m = -INFINITY;
        for (int e = eb; e < eb + 32; ++e) {
            int r = srow[e];
            if (r != cur) {
                atomicMax(&agg[(size_t)cur * HD + j], enc_f(m));
                cur = r; m = -INFINITY;
            }
            m = fmaxf(m, ein[e][j]);
        }
        atomicMax(&agg[(size_t)cur * HD + j], enc_f(m));
    }
}

// out = decode(agg) @ gw + gb, empty rows -> 0
__launch_bounds__(256, 4)
__global__ void k_out(const unsigned* __restrict__ agg, const float* __restrict__ gw,
                      const float* __restrict__ gb, float* __restrict__ out) {
    __shared__ float a[32][HD];
    const int t = threadIdx.x;
    const int m0 = blockIdx.x * 32;
    for (int i = t; i < 32 * HD; i += 256) {
        unsigned e = agg[(size_t)m0 * HD + i];
        a[i >> 7][i & 127] = (e == ENC_NEG_INF) ? 0.0f : dec_f(e);
    }
    __syncthreads();
    const int j4 = (t & 63) * 4;
    const int rbase = (t >> 6) * 8;
    float acc[8][4];
    const float4 bias = *(const float4*)&gb[j4];
    #pragma unroll
    for (int r = 0; r < 8; ++r) { acc[r][0] = bias.x; acc[r][1] = bias.y; acc[r][2] = bias.z; acc[r][3] = bias.w; }
    for (int k = 0; k < 128; k += 4) {
        float4 w0 = *(const float4*)&gw[(k + 0) * OD + j4];
        float4 w1 = *(const float4*)&gw[(k + 1) * OD + j4];
        float4 w2 = *(const float4*)&gw[(k + 2) * OD + j4];
        float4 w3 = *(const float4*)&gw[(k + 3) * OD + j4];
        #pragma unroll
        for (int r = 0; r < 8; ++r) {
            float4 av = *(const float4*)&a[rbase + r][k];
            acc[r][0] += av.x * w0.x + av.y * w1.x + av.z * w2.x + av.w * w3.x;
            acc[r][1] += av.x * w0.y + av.y * w1.y + av.z * w2.y + av.w * w3.y;
            acc[r][2] += av.x * w0.z + av.y * w1.z + av.z * w2.z + av.w * w3.z;
            acc[r][3] += av.x * w0.w + av.y * w1.w + av.z * w2.w + av.w * w3.w;
        }
    }
    #pragma unroll
    for (int r = 0; r < 8; ++r) {
        float4 v; v.x = acc[r][0]; v.y = acc[r][1]; v.z = acc[r][2]; v.w = acc[r][3];
        *(float4*)&out[(size_t)(m0 + rbase + r) * OD + j4] = v;
    }
}

extern "C" void kernel_launch(void* const* d_in, const int* in_sizes, int n_in,
                              void* d_out, int out_size, void* d_ws, size_t ws_size,
                              hipStream_t stream) {
    const float* x   = (const float*)d_in[0];
    const float* pos = (const float*)d_in[1];
    const int* batch = (const int*)d_in[2];
    const int* idx   = (const int*)d_in[3];
    const int* row   = (const int*)d_in[4];
    const int* col   = (const int*)d_in[5];
    const float* lw1 = (const float*)d_in[6];
    const float* lb1 = (const float*)d_in[7];
    const float* lw2 = (const float*)d_in[8];
    const float* lb2 = (const float*)d_in[9];
    const float* gw  = (const float*)d_in[10];
    const float* gb  = (const float*)d_in[11];
    float* out = (float*)d_out;
    unsigned* agg = (unsigned*)d_ws;  // needs MM*HD*4 = 8 MB

    hipLaunchKernelGGL(k_init, dim3((MM * HD + 255) / 256), dim3(256), 0, stream, agg);
    hipLaunchKernelGGL(k_prep, dim3((MM + 255) / 256), dim3(256), 0, stream, pos, batch, idx, out);
    hipLaunchKernelGGL(k_edge, dim3(EE / 64), dim3(256), 0, stream,
                       x, pos, idx, row, col, lw1, lb1, lw2, lb2, agg);
    hipLaunchKernelGGL(k_out, dim3(MM / 32), dim3(256), 0, stream, agg, gw, gb, out);
}

// Round 2
// 145.894 us; speedup vs baseline: 3.9011x; 3.9011x over previous
//
#include <hip/hip_runtime.h>
#include <math.h>

#define NN 65536
#define MM 16384
#define EE 524288
#define CF 64
#define HD 128
#define OD 256
#define LDB 136  // padded LDS row stride in bf16 elems: 272B = +4 banks/row rotation

typedef __bf16 bf16x8 __attribute__((ext_vector_type(8)));
typedef float f32x4 __attribute__((ext_vector_type(4)));

// order-isomorphic float->uint encoding so segment-max can use atomicMax(uint)
__device__ __forceinline__ unsigned enc_f(float f) {
    unsigned u = __float_as_uint(f);
    return (u & 0x80000000u) ? ~u : (u | 0x80000000u);
}
__device__ __forceinline__ float dec_f(unsigned e) {
    unsigned u = (e & 0x80000000u) ? (e ^ 0x80000000u) : ~e;
    return __uint_as_float(u);
}
#define ENC_NEG_INF 0x007FFFFFu  // enc(-inf)

__global__ void k_init(unsigned* __restrict__ agg) {
    int i = blockIdx.x * 256 + threadIdx.x;
    if (i < MM * HD) agg[i] = ENC_NEG_INF;
}

__global__ void k_prep(const float* __restrict__ pos, const int* __restrict__ batch,
                       const int* __restrict__ idx, float* __restrict__ out) {
    int m = blockIdx.x * 256 + threadIdx.x;
    if (m >= MM) return;
    int s = idx[m];
    out[MM * OD + m * 3 + 0] = pos[s * 3 + 0];
    out[MM * OD + m * 3 + 1] = pos[s * 3 + 1];
    out[MM * OD + m * 3 + 2] = pos[s * 3 + 2];
    out[MM * OD + MM * 3 + m] = (float)batch[s];
}

// MFMA edge kernel: 64 edges/group, 4 groups/block, 4 waves (each owns 32 N-cols).
// edge_in = [ x[col] (64) | pd (3) | sin/cos interleaved (60) | pad ] = 128 bf16.
__launch_bounds__(256, 2)
__global__ void k_edge(const float* __restrict__ x, const float* __restrict__ pos,
                       const int* __restrict__ idx, const int* __restrict__ row,
                       const int* __restrict__ col,
                       const float* __restrict__ lw1, const float* __restrict__ lb1,
                       const float* __restrict__ lw2, const float* __restrict__ lb2,
                       unsigned* __restrict__ agg) {
    __shared__ __align__(16) __bf16 ein[64][LDB];   // edge_in, later reused for edge_feat
    __shared__ __align__(16) __bf16 hbuf[64][LDB];  // hidden
    __shared__ int srow[64];
    const int t = threadIdx.x;
    const int lane = t & 63;
    const int wv = t >> 6;          // wave id 0..3
    const int n0 = wv * 32;         // wave's output-column base
    const int q = lane >> 4;        // quarter-wave
    const int ln = lane & 15;

    // ---- weight B-fragments into registers (once per block) ----
    // frag element j holds W[k][n] with k = kk*32 + q*8 + j, n = n0 + nt*16 + ln.
    // A uses the same k-enumeration, so any internal HW k-permutation cancels.
    bf16x8 w1f[2][4], w2f[2][4];
    float b1[2], b2[2];
    #pragma unroll
    for (int nt = 0; nt < 2; ++nt) {
        const int n = n0 + nt * 16 + ln;
        b1[nt] = lb1[n];
        b2[nt] = lb2[n];
        #pragma unroll
        for (int kk = 0; kk < 4; ++kk) {
            #pragma unroll
            for (int j = 0; j < 8; ++j) {
                const int k = kk * 32 + q * 8 + j;
                w1f[nt][kk][j] = (__bf16)((k < 127) ? lw1[k * HD + n] : 0.0f);
                w2f[nt][kk][j] = (__bf16)lw2[k * HD + n];
            }
        }
    }

    for (int g = 0; g < 4; ++g) {
        const int e0 = (blockIdx.x * 4 + g) * 64;
        if (g) __syncthreads();  // previous seg-max done before overwriting ein

        // ---- stage x[col] -> ein[:,0:64] bf16 (4 threads/edge, 16 cols each) ----
        {
            const int e = t >> 2, part = t & 3;
            const int c = col[e0 + e];
            const float4* xr = (const float4*)(x + (size_t)c * CF);
            __bf16* dst = &ein[e][part * 16];
            #pragma unroll
            for (int s = 0; s < 4; ++s) {
                float4 v = xr[part * 4 + s];
                dst[s * 4 + 0] = (__bf16)v.x;
                dst[s * 4 + 1] = (__bf16)v.y;
                dst[s * 4 + 2] = (__bf16)v.z;
                dst[s * 4 + 3] = (__bf16)v.w;
            }
        }
        // ---- positional encoding -> ein[:,64:127], pad 127 ----
        if (t < 64) {
            const int e = t;
            const int r = row[e0 + e];
            srow[e] = r;
            const int c = col[e0 + e];
            const int s = idx[r];
            float pd[3];
            #pragma unroll
            for (int d = 0; d < 3; ++d) pd[d] = pos[c * 3 + d] - pos[s * 3 + d];
            ein[e][64] = (__bf16)pd[0];
            ein[e][65] = (__bf16)pd[1];
            ein[e][66] = (__bf16)pd[2];
            #pragma unroll
            for (int d = 0; d < 3; ++d) {
                float f = pd[d] * 3.14159265358979323846f;  // *2/step == coords*(pi*2^l) exactly
                #pragma unroll
                for (int l = 0; l < 10; ++l) {
                    float sv, cv;
                    sincosf(f, &sv, &cv);
                    ein[e][67 + d * 20 + l * 2 + 0] = (__bf16)sv;
                    ein[e][67 + d * 20 + l * 2 + 1] = (__bf16)cv;
                    f *= 2.0f;
                }
            }
            ein[e][127] = (__bf16)0.0f;  // K pad
        }
        __syncthreads();

        // ---- GEMM1: h = relu(ein @ lw1 + lb1) via MFMA 16x16x32 ----
        {
            f32x4 acc[4][2];
            #pragma unroll
            for (int mt = 0; mt < 4; ++mt)
                #pragma unroll
                for (int nt = 0; nt < 2; ++nt)
                    acc[mt][nt] = (f32x4){b1[nt], b1[nt], b1[nt], b1[nt]};
            #pragma unroll
            for (int mt = 0; mt < 4; ++mt) {
                #pragma unroll
                for (int kk = 0; kk < 4; ++kk) {
                    bf16x8 a = *(const bf16x8*)&ein[mt * 16 + ln][kk * 32 + q * 8];
                    acc[mt][0] = __builtin_amdgcn_mfma_f32_16x16x32_bf16(a, w1f[0][kk], acc[mt][0], 0, 0, 0);
                    acc[mt][1] = __builtin_amdgcn_mfma_f32_16x16x32_bf16(a, w1f[1][kk], acc[mt][1], 0, 0, 0);
                }
            }
            // C/D layout: col = ln (+16*nt+n0), row = mt*16 + q*4 + r
            #pragma unroll
            for (int mt = 0; mt < 4; ++mt)
                #pragma unroll
                for (int nt = 0; nt < 2; ++nt)
                    #pragma unroll
                    for (int r = 0; r < 4; ++r)
                        hbuf[mt * 16 + q * 4 + r][n0 + nt * 16 + ln] =
                            (__bf16)fmaxf(acc[mt][nt][r], 0.0f);
        }
        __syncthreads();

        // ---- GEMM2: ef = h @ lw2 + lb2 -> write bf16 into ein ----
        {
            f32x4 acc[4][2];
            #pragma unroll
            for (int mt = 0; mt < 4; ++mt)
                #pragma unroll
                for (int nt = 0; nt < 2; ++nt)
                    acc[mt][nt] = (f32x4){b2[nt], b2[nt], b2[nt], b2[nt]};
            #pragma unroll
            for (int mt = 0; mt < 4; ++mt) {
                #pragma unroll
                for (int kk = 0; kk < 4; ++kk) {
                    bf16x8 a = *(const bf16x8*)&hbuf[mt * 16 + ln][kk * 32 + q * 8];
                    acc[mt][0] = __builtin_amdgcn_mfma_f32_16x16x32_bf16(a, w2f[0][kk], acc[mt][0], 0, 0, 0);
                    acc[mt][1] = __builtin_amdgcn_mfma_f32_16x16x32_bf16(a, w2f[1][kk], acc[mt][1], 0, 0, 0);
                }
            }
            #pragma unroll
            for (int mt = 0; mt < 4; ++mt)
                #pragma unroll
                for (int nt = 0; nt < 2; ++nt)
                    #pragma unroll
                    for (int r = 0; r < 4; ++r)
                        ein[mt * 16 + q * 4 + r][n0 + nt * 16 + ln] = (__bf16)acc[mt][nt][r];
        }
        __syncthreads();

        // ---- segment max (row sorted): one atomic per (row, feature) run ----
        {
            const int j = t & 127;
            const int eb = (t >> 7) * 32;
            int cur = srow[eb];
            float m = -INFINITY;
            for (int e = eb; e < eb + 32; ++e) {
                const int r = srow[e];
                if (r != cur) {
                    atomicMax(&agg[(size_t)cur * HD + j], enc_f(m));
                    cur = r; m = -INFINITY;
                }
                m = fmaxf(m, (float)ein[e][j]);
            }
            atomicMax(&agg[(size_t)cur * HD + j], enc_f(m));
        }
    }
}

// out = decode(agg) @ gw + gb, empty rows -> 0
__launch_bounds__(256, 4)
__global__ void k_out(const unsigned* __restrict__ agg, const float* __restrict__ gw,
                      const float* __restrict__ gb, float* __restrict__ out) {
    __shared__ float a[32][HD];
    const int t = threadIdx.x;
    const int m0 = blockIdx.x * 32;
    for (int i = t; i < 32 * HD; i += 256) {
        unsigned e = agg[(size_t)m0 * HD + i];
        a[i >> 7][i & 127] = (e == ENC_NEG_INF) ? 0.0f : dec_f(e);
    }
    __syncthreads();
    const int j4 = (t & 63) * 4;
    const int rbase = (t >> 6) * 8;
    float acc[8][4];
    const float4 bias = *(const float4*)&gb[j4];
    #pragma unroll
    for (int r = 0; r < 8; ++r) { acc[r][0] = bias.x; acc[r][1] = bias.y; acc[r][2] = bias.z; acc[r][3] = bias.w; }
    for (int k = 0; k < 128; k += 4) {
        float4 w0 = *(const float4*)&gw[(k + 0) * OD + j4];
        float4 w1 = *(const float4*)&gw[(k + 1) * OD + j4];
        float4 w2 = *(const float4*)&gw[(k + 2) * OD + j4];
        float4 w3 = *(const float4*)&gw[(k + 3) * OD + j4];
        #pragma unroll
        for (int r = 0; r < 8; ++r) {
            float4 av = *(const float4*)&a[rbase + r][k];
            acc[r][0] += av.x * w0.x + av.y * w1.x + av.z * w2.x + av.w * w3.x;
            acc[r][1] += av.x * w0.y + av.y * w1.y + av.z * w2.y + av.w * w3.y;
            acc[r][2] += av.x * w0.z + av.y * w1.z + av.z * w2.z + av.w * w3.z;
            acc[r][3] += av.x * w0.w + av.y * w1.w + av.z * w2.w + av.w * w3.w;
        }
    }
    #pragma unroll
    for (int r = 0; r < 8; ++r) {
        float4 v; v.x = acc[r][0]; v.y = acc[r][1]; v.z = acc[r][2]; v.w = acc[r][3];
        *(float4*)&out[(size_t)(m0 + rbase + r) * OD + j4] = v;
    }
}

extern "C" void kernel_launch(void* const* d_in, const int* in_sizes, int n_in,
                              void* d_out, int out_size, void* d_ws, size_t ws_size,
                              hipStream_t stream) {
    const float* x   = (const float*)d_in[0];
    const float* pos = (const float*)d_in[1];
    const int* batch = (const int*)d_in[2];
    const int* idx   = (const int*)d_in[3];
    const int* row   = (const int*)d_in[4];
    const int* col   = (const int*)d_in[5];
    const float* lw1 = (const float*)d_in[6];
    const float* lb1 = (const float*)d_in[7];
    const float* lw2 = (const float*)d_in[8];
    const float* lb2 = (const float*)d_in[9];
    const float* gw  = (const float*)d_in[10];
    const float* gb  = (const float*)d_in[11];
    float* out = (float*)d_out;
    unsigned* agg = (unsigned*)d_ws;  // MM*HD*4 = 8 MB

    hipLaunchKernelGGL(k_init, dim3((MM * HD + 255) / 256), dim3(256), 0, stream, agg);
    hipLaunchKernelGGL(k_prep, dim3((MM + 255) / 256), dim3(256), 0, stream, pos, batch, idx, out);
    hipLaunchKernelGGL(k_edge, dim3(EE / 256), dim3(256), 0, stream,
                       x, pos, idx, row, col, lw1, lb1, lw2, lb2, agg);
    hipLaunchKernelGGL(k_out, dim3(MM / 32), dim3(256), 0, stream, agg, gw, gb, out);
}